// Round 6
// baseline (81.969 us; speedup 1.0000x reference)
//
#include <hip/hip_runtime.h>

constexpr int M_ROWS = 16000;   // B*T
constexpr int DIM    = 512;
constexpr int NEXP   = 10;
constexpr int NSH    = 5;
constexpr int KTOP   = 5;

constexpr int TMA = 32;         // rows per gemm block
constexpr int NC  = 128;        // cols per gemm block (4 slices)
constexpr int BK  = 32;         // k-tile
constexpr int NT  = DIM / BK;   // 16

typedef __attribute__((ext_vector_type(8))) short  bf16x8;
typedef __attribute__((ext_vector_type(4))) float  f32x4;

__device__ inline unsigned short bf16_rne(float x) {
    unsigned u = __float_as_uint(x);
    u += 0x7fffu + ((u >> 16) & 1u);
    return (unsigned short)(u >> 16);
}
__device__ inline float bf16_to_f(unsigned short h) {
    return __uint_as_float(((unsigned)h) << 16);
}

// ---------------- prep: W1 -> (hi,lo) bf16 [N][K]; shsum = sum_s shared_w ----
__global__ __launch_bounds__(256)
void prep_kernel(const float* __restrict__ W1, const float* __restrict__ shared_w,
                 unsigned short* __restrict__ w1hi, unsigned short* __restrict__ w1lo,
                 float* __restrict__ shsum)
{
    int b = blockIdx.x;
    if (b < 256) {
        int f = b * 256 + threadIdx.x;
        float4 v = *reinterpret_cast<const float4*>(&W1[(size_t)f * 4]);
        float xs[4] = {v.x, v.y, v.z, v.w};
        ushort4 h4, l4;
        unsigned short h[4], l[4];
        #pragma unroll
        for (int i = 0; i < 4; ++i) {
            h[i] = bf16_rne(xs[i]);
            float rem = xs[i] - bf16_to_f(h[i]);
            l[i] = bf16_rne(rem);
        }
        h4.x = h[0]; h4.y = h[1]; h4.z = h[2]; h4.w = h[3];
        l4.x = l[0]; l4.y = l[1]; l4.z = l[2]; l4.w = l[3];
        *reinterpret_cast<ushort4*>(&w1hi[(size_t)f * 4]) = h4;
        *reinterpret_cast<ushort4*>(&w1lo[(size_t)f * 4]) = l4;
    } else {
        for (int c = threadIdx.x; c < DIM; c += 256) {
            float s = 0.f;
            #pragma unroll
            for (int e = 0; e < NSH; ++e) s += shared_w[e * DIM + c];
            shsum[c] = s;
        }
    }
}

// ---------------- kernel A: col-split GEMM + partial logits ----------------
// Grid: 500 row-blocks x 4 col-slices = 2000 blocks, 256 thr = 4 waves.
// Block: 32 rows x 128 cols. Wave wv -> 64-col group g=wv>>1 (cols
// [g*64, g*64+64) local), 16-row half h=wv&1 (rows [h*16, h*16+16)),
// acc[4 ct]. This reproduces round-4's per-wave 64-col logit fmaf-chain +
// butterfly BIT-EXACTLY (flip-safety); partials written in round-4 w-order.
// LDS 40960 B -> 4 blocks/CU = 16 waves/CU (the occupancy fix under test).
// LDS (shorts): Bh[2] @ 0/4096; Bl[2] @ 8192/12288; Ab[2] @ 16384/18432
//               (Ab buf: hi[32][32] @ +0, lo @ +1024).
// Chunk swizzle (16B chunks in 64B row): phys = logical ^ ((row>>1)&3),
// pre-swizzled gload_lds SOURCE + swizzled reads (both-sides rule).
__global__ __launch_bounds__(256, 4)
void gemm_logits(const float* __restrict__ G,
                 const unsigned short* __restrict__ w1hi,
                 const unsigned short* __restrict__ w1lo,
                 const float* __restrict__ W2,
                 float* __restrict__ plogG)
{
    __shared__ unsigned short smem[20480];   // 40960 B

    const int tid  = threadIdx.x;
    const int lane = tid & 63;
    const int wv   = tid >> 6;          // 0..3
    const int l15  = lane & 15;
    const int lg   = lane >> 4;
    const int gsel = wv >> 1;           // 64-col group within block
    const int hsel = wv & 1;            // 16-row half
    const int bx    = blockIdx.x;
    const int slice = bx & 3;
    const int row0  = (bx >> 2) * TMA;
    const int cb    = slice * NC;       // global col base

    const int arow = tid >> 3;          // 0..31
    const int aq   = tid & 7;
    const int acol = ((aq >> 1) ^ ((arow >> 1) & 3)) * 8 + (aq & 1) * 4;

    f32x4 acc[4];
    #pragma unroll
    for (int ct = 0; ct < 4; ++ct) acc[ct] = (f32x4)0.f;

    auto stageB = [&](int t, int buf) {
        unsigned short* bh = smem + buf * 4096;
        unsigned short* bl = smem + 8192 + buf * 4096;
        #pragma unroll
        for (int r = 0; r < 2; ++r) {
            int f = r * 256 + tid;       // 0..511 chunks
            int n = f >> 2;              // local col 0..127
            int j = f & 3;
            int js = j ^ ((n >> 1) & 3);
            __builtin_amdgcn_global_load_lds(
                (const __attribute__((address_space(1))) void*)(w1hi + (size_t)(cb + n) * DIM + t * BK + js * 8),
                (__attribute__((address_space(3))) void*)(bh + f * 8), 16, 0, 0);
        }
        #pragma unroll
        for (int r = 0; r < 2; ++r) {
            int f = r * 256 + tid;
            int n = f >> 2;
            int j = f & 3;
            int js = j ^ ((n >> 1) & 3);
            __builtin_amdgcn_global_load_lds(
                (const __attribute__((address_space(1))) void*)(w1lo + (size_t)(cb + n) * DIM + t * BK + js * 8),
                (__attribute__((address_space(3))) void*)(bl + f * 8), 16, 0, 0);
        }
    };
    auto stageA = [&](int t, int buf) {
        float4 g4 = *reinterpret_cast<const float4*>(
                        &G[(size_t)(row0 + arow) * DIM + t * BK + aq * 4]);
        float xs[4] = {g4.x, g4.y, g4.z, g4.w};
        unsigned short h[4], l[4];
        #pragma unroll
        for (int i = 0; i < 4; ++i) {
            h[i] = bf16_rne(xs[i]);
            float rem = xs[i] - bf16_to_f(h[i]);
            l[i] = bf16_rne(rem);
        }
        ushort4 h4, l4;
        h4.x = h[0]; h4.y = h[1]; h4.z = h[2]; h4.w = h[3];
        l4.x = l[0]; l4.y = l[1]; l4.z = l[2]; l4.w = l[3];
        unsigned short* ab = smem + 16384 + buf * 2048;
        *reinterpret_cast<ushort4*>(&ab[arow * 32 + acol])        = h4;
        *reinterpret_cast<ushort4*>(&ab[1024 + arow * 32 + acol]) = l4;
    };

    stageB(0, 0);
    stageA(0, 0);
    __syncthreads();

    for (int t = 0; t < NT; ++t) {
        const int cur = t & 1;
        if (t + 1 < NT) {
            stageB(t + 1, cur ^ 1);
            stageA(t + 1, cur ^ 1);
        }
        unsigned short* ab  = smem + 16384 + cur * 2048;
        unsigned short* bhb = smem + cur * 4096;
        unsigned short* blb = smem + 8192 + cur * 4096;

        bf16x8 ah, al, bh[4], bl[4];
        {
            int r_ = hsel * 16 + l15;
            int cs = (lg ^ ((r_ >> 1) & 3)) * 8;
            ah = *reinterpret_cast<const bf16x8*>(&ab[r_ * 32 + cs]);
            al = *reinterpret_cast<const bf16x8*>(&ab[1024 + r_ * 32 + cs]);
        }
        #pragma unroll
        for (int ct = 0; ct < 4; ++ct) {
            int n  = gsel * 64 + ct * 16 + l15;
            int cs = (lg ^ ((n >> 1) & 3)) * 8;
            bh[ct] = *reinterpret_cast<const bf16x8*>(&bhb[n * 32 + cs]);
            bl[ct] = *reinterpret_cast<const bf16x8*>(&blb[n * 32 + cs]);
        }
        // per-acc pass order (hh, lh, hl) == round 4 (bit-exact h)
        #pragma unroll
        for (int ct = 0; ct < 4; ++ct)
            acc[ct] = __builtin_amdgcn_mfma_f32_16x16x32_bf16(ah, bh[ct], acc[ct], 0, 0, 0);
        #pragma unroll
        for (int ct = 0; ct < 4; ++ct)
            acc[ct] = __builtin_amdgcn_mfma_f32_16x16x32_bf16(al, bh[ct], acc[ct], 0, 0, 0);
        #pragma unroll
        for (int ct = 0; ct < 4; ++ct)
            acc[ct] = __builtin_amdgcn_mfma_f32_16x16x32_bf16(ah, bl[ct], acc[ct], 0, 0, 0);
        __syncthreads();
    }

    // ReLU
    #pragma unroll
    for (int ct = 0; ct < 4; ++ct)
        #pragma unroll
        for (int j = 0; j < 4; ++j)
            acc[ct][j] = fmaxf(acc[ct][j], 0.f);

    // per-wave 64-col logit partial, round-4 bit-exact tree:
    // s = fmaf chain over ct=0..3 from 0, then width-16 butterfly (xor 1,2,4,8)
    const int w8 = slice * 2 + gsel;    // round-4 wave index (col group w8*64)
    #pragma unroll
    for (int e = 0; e < NEXP; ++e) {
        float w2v[4];
        #pragma unroll
        for (int ct = 0; ct < 4; ++ct)
            w2v[ct] = W2[(size_t)e * DIM + cb + gsel * 64 + ct * 16 + l15];
        #pragma unroll
        for (int j = 0; j < 4; ++j) {
            float s = 0.f;
            #pragma unroll
            for (int ct = 0; ct < 4; ++ct)
                s = fmaf(acc[ct][j], w2v[ct], s);
            s += __shfl_xor(s, 1, 16);
            s += __shfl_xor(s, 2, 16);
            s += __shfl_xor(s, 4, 16);
            s += __shfl_xor(s, 8, 16);
            if (l15 == 0) {
                int grow = row0 + hsel * 16 + lg * 4 + j;
                plogG[((size_t)grow * 8 + w8) * NEXP + e] = s;
            }
        }
    }
}

// ---------------- kernel B: reduce 8 partials + softmax/top-5 + output -----
__global__ __launch_bounds__(256)
void finalize(const float* __restrict__ plogG, const float* __restrict__ value,
              const float* __restrict__ shsum, const float* __restrict__ routing_w,
              float* __restrict__ out)
{
    __shared__ float swls[TMA * NEXP];
    const int tid  = threadIdx.x;
    const int row0 = blockIdx.x * TMA;

    if (tid < TMA) {
        const float* pr = &plogG[(size_t)(row0 + tid) * 8 * NEXP];
        float lgt[NEXP];
        #pragma unroll
        for (int e = 0; e < NEXP; ++e) lgt[e] = 0.f;
        #pragma unroll
        for (int w = 0; w < 8; ++w)        // sequential w-order == round 4
            #pragma unroll
            for (int e = 0; e < NEXP; ++e)
                lgt[e] += pr[w * NEXP + e];

        float mx = lgt[0];
        #pragma unroll
        for (int e = 1; e < NEXP; ++e) mx = fmaxf(mx, lgt[e]);
        float p[NEXP], se = 0.f;
        #pragma unroll
        for (int e = 0; e < NEXP; ++e) { p[e] = expf(lgt[e] - mx); se += p[e]; }
        float inv = 1.f / se;
        #pragma unroll
        for (int e = 0; e < NEXP; ++e) p[e] *= inv;
        unsigned used = 0;
        #pragma unroll
        for (int t = 0; t < KTOP; ++t) {
            float bv = -1.f; int bi = 0;
            #pragma unroll
            for (int e = 0; e < NEXP; ++e) {
                bool better = (((used >> e) & 1u) == 0u) && (p[e] > bv);
                bv = better ? p[e] : bv;
                bi = better ? e : bi;
            }
            used |= 1u << bi;
        }
        #pragma unroll
        for (int e = 0; e < NEXP; ++e)
            swls[tid * NEXP + e] = ((used >> e) & 1u) ? p[e] : 0.f;
    }
    __syncthreads();

    const int c4 = (tid & 127) * 4;
    const int rh = tid >> 7;                       // 0/1 -> rows rh*16..+15
    float4 sh4 = *reinterpret_cast<const float4*>(&shsum[c4]);
    float4 rw4[NEXP];
    #pragma unroll
    for (int e = 0; e < NEXP; ++e)
        rw4[e] = *reinterpret_cast<const float4*>(&routing_w[(size_t)e * DIM + c4]);
    #pragma unroll
    for (int r = 0; r < 16; ++r) {
        int row = rh * 16 + r;
        float val = value[row0 + row];
        float4 o = sh4;
        #pragma unroll
        for (int e = 0; e < NEXP; ++e) {
            float wgt = swls[row * NEXP + e];
            o.x = fmaf(wgt, rw4[e].x, o.x);
            o.y = fmaf(wgt, rw4[e].y, o.y);
            o.z = fmaf(wgt, rw4[e].z, o.z);
            o.w = fmaf(wgt, rw4[e].w, o.w);
        }
        o.x *= val; o.y *= val; o.z *= val; o.w *= val;
        *reinterpret_cast<float4*>(&out[(size_t)(row0 + row) * DIM + c4]) = o;
    }
}

extern "C" void kernel_launch(void* const* d_in, const int* in_sizes, int n_in,
                              void* d_out, int out_size, void* d_ws, size_t ws_size,
                              hipStream_t stream) {
    const float* G         = (const float*)d_in[0];
    const float* value     = (const float*)d_in[1];
    const float* shared_w  = (const float*)d_in[2];
    const float* routing_w = (const float*)d_in[3];
    const float* W1        = (const float*)d_in[4];
    const float* W2        = (const float*)d_in[5];
    float* out             = (float*)d_out;

    unsigned short* w1hi = (unsigned short*)d_ws;                        // 512 KB
    unsigned short* w1lo = (unsigned short*)((char*)d_ws + 524288);      // 512 KB
    float*          shs  = (float*)((char*)d_ws + 1048576);              // 2 KB
    float*          plg  = (float*)((char*)d_ws + 1056768);              // 5.12 MB [M][8][10]

    prep_kernel<<<257, 256, 0, stream>>>(W1, shared_w, w1hi, w1lo, shs);
    gemm_logits<<<(M_ROWS / TMA) * 4, 256, 0, stream>>>(G, w1hi, w1lo, W2, plg);
    finalize<<<M_ROWS / TMA, 256, 0, stream>>>(plg, value, shs, routing_w, out);
}

// Round 7
// 61.486 us; speedup vs baseline: 1.3331x; 1.3331x over previous
//
#include <hip/hip_runtime.h>

constexpr int M_ROWS = 16000;   // B*T
constexpr int DIM    = 512;
constexpr int NEXP   = 10;
constexpr int NSH    = 5;
constexpr int KTOP   = 5;

constexpr int TMA = 64;         // rows per gemm block
constexpr int NCB = 256;        // cols per gemm block (2 col-blocks)
constexpr int BK  = 32;         // k-tile
constexpr int NT  = DIM / BK;   // 16

constexpr int TMF = 32;         // rows per finalize block

typedef __attribute__((ext_vector_type(8))) short  bf16x8;
typedef __attribute__((ext_vector_type(4))) float  f32x4;

__device__ inline unsigned short bf16_rne(float x) {
    unsigned u = __float_as_uint(x);
    u += 0x7fffu + ((u >> 16) & 1u);
    return (unsigned short)(u >> 16);
}
__device__ inline float bf16_to_f(unsigned short h) {
    return __uint_as_float(((unsigned)h) << 16);
}

// ---------------- prep: W1 -> (hi,lo) bf16 [N][K]; shsum = sum_s shared_w ----
__global__ __launch_bounds__(256)
void prep_kernel(const float* __restrict__ W1, const float* __restrict__ shared_w,
                 unsigned short* __restrict__ w1hi, unsigned short* __restrict__ w1lo,
                 float* __restrict__ shsum)
{
    int b = blockIdx.x;
    if (b < 256) {
        int f = b * 256 + threadIdx.x;
        float4 v = *reinterpret_cast<const float4*>(&W1[(size_t)f * 4]);
        float xs[4] = {v.x, v.y, v.z, v.w};
        ushort4 h4, l4;
        unsigned short h[4], l[4];
        #pragma unroll
        for (int i = 0; i < 4; ++i) {
            h[i] = bf16_rne(xs[i]);
            float rem = xs[i] - bf16_to_f(h[i]);
            l[i] = bf16_rne(rem);
        }
        h4.x = h[0]; h4.y = h[1]; h4.z = h[2]; h4.w = h[3];
        l4.x = l[0]; l4.y = l[1]; l4.z = l[2]; l4.w = l[3];
        *reinterpret_cast<ushort4*>(&w1hi[(size_t)f * 4]) = h4;
        *reinterpret_cast<ushort4*>(&w1lo[(size_t)f * 4]) = l4;
    } else {
        for (int c = threadIdx.x; c < DIM; c += 256) {
            float s = 0.f;
            #pragma unroll
            for (int e = 0; e < NSH; ++e) s += shared_w[e * DIM + c];
            shsum[c] = s;
        }
    }
}

// ---------------- kernel A: GEMM + partial logits ----------------
// Grid: 250 row-blocks x 2 col-blocks = 500 blocks, 512 thr = 8 waves.
// Block: 64 rows x 256 cols. Wave wv: row-group rgrp=wv>>2 (rows rgrp*32+..),
// col-group cgrp=wv&3 (cols cgrp*64+..): 32r x 64c, acc[2 rt][4 ct].
// 12 ds_read_b128 -> 24 MFMA per wave per k-tile (2x round-6 economy).
// LDS dbuf 2 x 40 KB = 80 KB -> 2 blocks/CU = 16 waves/CU.
// Per buf (shorts): Bh[256][32] @ +0, Bl @ +8192, Ah[64][32] @ +16384,
//                   Al @ +18432.  Chunk swizzle: phys16B = logical ^ ((row>>1)&3),
// pre-swizzled gload_lds SOURCE + swizzled reads (both-sides rule).
// BIT-EXACT logit invariants (verified rounds 4/6): 16x16x32 bf16 MFMA,
// k-chunks t ascending, per-acc pass order (hh,lh,hl), per-(row,64col-group)
// fmaf chain over ct=0..3 + width-16 butterfly, finalize sums w8=0..7.
__global__ __launch_bounds__(512, 4)
void gemm_logits(const float* __restrict__ G,
                 const unsigned short* __restrict__ w1hi,
                 const unsigned short* __restrict__ w1lo,
                 const float* __restrict__ W2,
                 float* __restrict__ plogG)
{
    __shared__ unsigned short smem[40960];   // 81920 B

    const int tid  = threadIdx.x;
    const int lane = tid & 63;
    const int wv   = tid >> 6;          // 0..7
    const int l15  = lane & 15;
    const int lg   = lane >> 4;
    const int rgrp = wv >> 2;           // 0..1
    const int cgrp = wv & 3;            // 0..3
    const int bx     = blockIdx.x;
    const int colblk = bx & 1;
    const int row0   = (bx >> 1) * TMA;
    const int cb     = colblk * NCB;    // global col base

    const int arow = tid >> 3;          // 0..63
    const int aq   = tid & 7;
    const int acol = ((aq >> 1) ^ ((arow >> 1) & 3)) * 8 + (aq & 1) * 4;

    f32x4 acc[2][4];
    #pragma unroll
    for (int rt = 0; rt < 2; ++rt)
        #pragma unroll
        for (int ct = 0; ct < 4; ++ct) acc[rt][ct] = (f32x4)0.f;

    auto stageB = [&](int t, int buf) {
        unsigned short* bh = smem + buf * 20480;
        unsigned short* bl = bh + 8192;
        #pragma unroll
        for (int r = 0; r < 2; ++r) {
            int f = r * 512 + tid;       // 0..1023 chunks
            int n = f >> 2;              // local col 0..255
            int j = f & 3;
            int js = j ^ ((n >> 1) & 3);
            __builtin_amdgcn_global_load_lds(
                (const __attribute__((address_space(1))) void*)(w1hi + (size_t)(cb + n) * DIM + t * BK + js * 8),
                (__attribute__((address_space(3))) void*)(bh + f * 8), 16, 0, 0);
        }
        #pragma unroll
        for (int r = 0; r < 2; ++r) {
            int f = r * 512 + tid;
            int n = f >> 2;
            int j = f & 3;
            int js = j ^ ((n >> 1) & 3);
            __builtin_amdgcn_global_load_lds(
                (const __attribute__((address_space(1))) void*)(w1lo + (size_t)(cb + n) * DIM + t * BK + js * 8),
                (__attribute__((address_space(3))) void*)(bl + f * 8), 16, 0, 0);
        }
    };
    auto stageA = [&](int t, int buf) {
        float4 g4 = *reinterpret_cast<const float4*>(
                        &G[(size_t)(row0 + arow) * DIM + t * BK + aq * 4]);
        float xs[4] = {g4.x, g4.y, g4.z, g4.w};
        unsigned short h[4], l[4];
        #pragma unroll
        for (int i = 0; i < 4; ++i) {
            h[i] = bf16_rne(xs[i]);
            float rem = xs[i] - bf16_to_f(h[i]);
            l[i] = bf16_rne(rem);
        }
        ushort4 h4, l4;
        h4.x = h[0]; h4.y = h[1]; h4.z = h[2]; h4.w = h[3];
        l4.x = l[0]; l4.y = l[1]; l4.z = l[2]; l4.w = l[3];
        unsigned short* ab = smem + buf * 20480 + 16384;
        *reinterpret_cast<ushort4*>(&ab[arow * 32 + acol])        = h4;
        *reinterpret_cast<ushort4*>(&ab[2048 + arow * 32 + acol]) = l4;
    };

    stageB(0, 0);
    stageA(0, 0);
    __syncthreads();

    for (int t = 0; t < NT; ++t) {
        const int cur = t & 1;
        if (t + 1 < NT) {
            stageB(t + 1, cur ^ 1);
            stageA(t + 1, cur ^ 1);
        }
        unsigned short* base = smem + cur * 20480;

        bf16x8 ah[2], al[2], bh[4], bl[4];
        #pragma unroll
        for (int rt = 0; rt < 2; ++rt) {
            int r_ = rgrp * 32 + rt * 16 + l15;
            int cs = (lg ^ ((r_ >> 1) & 3)) * 8;
            ah[rt] = *reinterpret_cast<const bf16x8*>(&base[16384 + r_ * 32 + cs]);
            al[rt] = *reinterpret_cast<const bf16x8*>(&base[18432 + r_ * 32 + cs]);
        }
        #pragma unroll
        for (int ct = 0; ct < 4; ++ct) {
            int n  = cgrp * 64 + ct * 16 + l15;
            int cs = (lg ^ ((n >> 1) & 3)) * 8;
            bh[ct] = *reinterpret_cast<const bf16x8*>(&base[n * 32 + cs]);
            bl[ct] = *reinterpret_cast<const bf16x8*>(&base[8192 + n * 32 + cs]);
        }
        // per-acc pass order (hh, lh, hl) == rounds 4/6 (bit-exact h)
        #pragma unroll
        for (int ct = 0; ct < 4; ++ct)
            #pragma unroll
            for (int rt = 0; rt < 2; ++rt)
                acc[rt][ct] = __builtin_amdgcn_mfma_f32_16x16x32_bf16(ah[rt], bh[ct], acc[rt][ct], 0, 0, 0);
        #pragma unroll
        for (int ct = 0; ct < 4; ++ct)
            #pragma unroll
            for (int rt = 0; rt < 2; ++rt)
                acc[rt][ct] = __builtin_amdgcn_mfma_f32_16x16x32_bf16(al[rt], bh[ct], acc[rt][ct], 0, 0, 0);
        #pragma unroll
        for (int ct = 0; ct < 4; ++ct)
            #pragma unroll
            for (int rt = 0; rt < 2; ++rt)
                acc[rt][ct] = __builtin_amdgcn_mfma_f32_16x16x32_bf16(ah[rt], bl[ct], acc[rt][ct], 0, 0, 0);
        __syncthreads();
    }

    // ReLU
    #pragma unroll
    for (int rt = 0; rt < 2; ++rt)
        #pragma unroll
        for (int ct = 0; ct < 4; ++ct)
            #pragma unroll
            for (int j = 0; j < 4; ++j)
                acc[rt][ct][j] = fmaxf(acc[rt][ct][j], 0.f);

    // per-wave 64-col logit partial, bit-exact tree:
    // fmaf chain over ct=0..3 from 0, then width-16 butterfly (xor 1,2,4,8)
    const int w8 = colblk * 4 + cgrp;   // 64-col group index 0..7
    #pragma unroll
    for (int e = 0; e < NEXP; ++e) {
        float w2v[4];
        #pragma unroll
        for (int ct = 0; ct < 4; ++ct)
            w2v[ct] = W2[(size_t)e * DIM + cb + cgrp * 64 + ct * 16 + l15];
        #pragma unroll
        for (int rt = 0; rt < 2; ++rt) {
            #pragma unroll
            for (int j = 0; j < 4; ++j) {
                float s = 0.f;
                #pragma unroll
                for (int ct = 0; ct < 4; ++ct)
                    s = fmaf(acc[rt][ct][j], w2v[ct], s);
                s += __shfl_xor(s, 1, 16);
                s += __shfl_xor(s, 2, 16);
                s += __shfl_xor(s, 4, 16);
                s += __shfl_xor(s, 8, 16);
                if (l15 == 0) {
                    int grow = row0 + rgrp * 32 + rt * 16 + lg * 4 + j;
                    plogG[((size_t)grow * 8 + w8) * NEXP + e] = s;
                }
            }
        }
    }
}

// ---------------- kernel B: reduce 8 partials + softmax/top-5 + output -----
__global__ __launch_bounds__(256)
void finalize(const float* __restrict__ plogG, const float* __restrict__ value,
              const float* __restrict__ shsum, const float* __restrict__ routing_w,
              float* __restrict__ out)
{
    __shared__ float swls[TMF * NEXP];
    const int tid  = threadIdx.x;
    const int row0 = blockIdx.x * TMF;

    if (tid < TMF) {
        const float* pr = &plogG[(size_t)(row0 + tid) * 8 * NEXP];
        float lgt[NEXP];
        #pragma unroll
        for (int e = 0; e < NEXP; ++e) lgt[e] = 0.f;
        #pragma unroll
        for (int w = 0; w < 8; ++w)        // sequential w-order (bit-exact)
            #pragma unroll
            for (int e = 0; e < NEXP; ++e)
                lgt[e] += pr[w * NEXP + e];

        float mx = lgt[0];
        #pragma unroll
        for (int e = 1; e < NEXP; ++e) mx = fmaxf(mx, lgt[e]);
        float p[NEXP], se = 0.f;
        #pragma unroll
        for (int e = 0; e < NEXP; ++e) { p[e] = expf(lgt[e] - mx); se += p[e]; }
        float inv = 1.f / se;
        #pragma unroll
        for (int e = 0; e < NEXP; ++e) p[e] *= inv;
        unsigned used = 0;
        #pragma unroll
        for (int t = 0; t < KTOP; ++t) {
            float bv = -1.f; int bi = 0;
            #pragma unroll
            for (int e = 0; e < NEXP; ++e) {
                bool better = (((used >> e) & 1u) == 0u) && (p[e] > bv);
                bv = better ? p[e] : bv;
                bi = better ? e : bi;
            }
            used |= 1u << bi;
        }
        #pragma unroll
        for (int e = 0; e < NEXP; ++e)
            swls[tid * NEXP + e] = ((used >> e) & 1u) ? p[e] : 0.f;
    }
    __syncthreads();

    const int c4 = (tid & 127) * 4;
    const int rh = tid >> 7;                       // 0/1 -> rows rh*16..+15
    float4 sh4 = *reinterpret_cast<const float4*>(&shsum[c4]);
    float4 rw4[NEXP];
    #pragma unroll
    for (int e = 0; e < NEXP; ++e)
        rw4[e] = *reinterpret_cast<const float4*>(&routing_w[(size_t)e * DIM + c4]);
    #pragma unroll
    for (int r = 0; r < 16; ++r) {
        int row = rh * 16 + r;
        float val = value[row0 + row];
        float4 o = sh4;
        #pragma unroll
        for (int e = 0; e < NEXP; ++e) {
            float wgt = swls[row * NEXP + e];
            o.x = fmaf(wgt, rw4[e].x, o.x);
            o.y = fmaf(wgt, rw4[e].y, o.y);
            o.z = fmaf(wgt, rw4[e].z, o.z);
            o.w = fmaf(wgt, rw4[e].w, o.w);
        }
        o.x *= val; o.y *= val; o.z *= val; o.w *= val;
        *reinterpret_cast<float4*>(&out[(size_t)(row0 + row) * DIM + c4]) = o;
    }
}

extern "C" void kernel_launch(void* const* d_in, const int* in_sizes, int n_in,
                              void* d_out, int out_size, void* d_ws, size_t ws_size,
                              hipStream_t stream) {
    const float* G         = (const float*)d_in[0];
    const float* value     = (const float*)d_in[1];
    const float* shared_w  = (const float*)d_in[2];
    const float* routing_w = (const float*)d_in[3];
    const float* W1        = (const float*)d_in[4];
    const float* W2        = (const float*)d_in[5];
    float* out             = (float*)d_out;

    unsigned short* w1hi = (unsigned short*)d_ws;                        // 512 KB
    unsigned short* w1lo = (unsigned short*)((char*)d_ws + 524288);      // 512 KB
    float*          shs  = (float*)((char*)d_ws + 1048576);              // 2 KB
    float*          plg  = (float*)((char*)d_ws + 1056768);              // 5.12 MB [M][8][10]

    prep_kernel<<<257, 256, 0, stream>>>(W1, shared_w, w1hi, w1lo, shs);
    gemm_logits<<<(M_ROWS / TMA) * 2, 512, 0, stream>>>(G, w1hi, w1lo, W2, plg);
    finalize<<<M_ROWS / TMF, 256, 0, stream>>>(plg, value, shs, routing_w, out);
}